// Round 1
// 236.192 us; speedup vs baseline: 1.0129x; 1.0129x over previous
//
#include <hip/hip_runtime.h>

// Problem constants
#define LL    262144
#define GG    8
#define JJ    8
#define FGF   16
#define WW    31
#define PAD1  15
#define NB    512            // k positions per block (was 1024)
#define NTHR  256
#define XTLEN (NB + 32)      // 544 staged positions: x[nbase-16 .. nbase+NB+15]
#define NF4   (XTLEN / 4 * JJ)   // 1088 float4 staging loads per block

typedef __bf16 bf16x8 __attribute__((ext_vector_type(8)));
typedef float  f32x4  __attribute__((ext_vector_type(4)));

__device__ inline unsigned short f2bf(float f) {
    unsigned int u = __float_as_uint(f);
    u = (u + 0x7FFF + ((u >> 16) & 1)) >> 16;   // RNE
    return (unsigned short)u;
}

// MFMA kernel, operand-SWAPPED vs previous version:
//   acc = mfma(A = X-fragment, B = P-fragment)
// The 16x16x32 A/B lane mappings are symmetric (index = lane&15,
// k-chunk = (lane>>4)*8), so the staged fragments are IDENTICAL to the
// previous version -- only the argument order and the store indexing change.
// D layout (m89-verified): col = lane&15 (= filter), row = q*4 + reg
// (= position) -> each lane holds 4 CONSECUTIVE positions of one filter
// -> f32x4 stores (1 KB coalesced per instruction, 4x fewer store instrs).
//
// Rolling-window identity unchanged: frag(tile, s+4) == frag(tile+1, s).
__global__ __launch_bounds__(NTHR, 4)
void conv_mfma(const float* __restrict__ x, const float* __restrict__ p,
               const int* __restrict__ rel, float* __restrict__ out)
{
    __shared__ unsigned short pw[32 * 16 * 8];   // [w][f][j] bf16, w=31 zeroed (8 KB)
    __shared__ unsigned short xt[XTLEN * 8];     // [pos][j]  bf16 (8.5 KB)

    const int t = threadIdx.x;
    const int g = blockIdx.y;
    const long nbase = (long)blockIdx.x * NB;

    // ---- stage P: LINEAR LDS writes (previous layout had lanes stepping w =
    // 256B stride = ~32-way bank conflict; this is conflict-free). Global
    // reads are scattered but p[g] is 15.5 KB and L1/L2-hot across the 512
    // blocks per g.
    {
        const float* pg = p + (long)g * FGF * JJ * WW;
        #pragma unroll
        for (int k = 0; k < 16; ++k) {
            int i = t + k * NTHR;            // i = (w*16 + f)*8 + j
            int w = i >> 7;
            int f = (i >> 3) & 15;
            int j = i & 7;
            float v = (w < WW) ? pg[(f * JJ + j) * WW + w] : 0.0f;
            pw[i] = f2bf(v);
        }
    }

    // ---- stage x: float4 COALESCED global loads (was scalar), 4 b16 LDS
    // writes each. xt[pos][j] = bf16(x[rel[g,j], nbase - 16 + pos])
    {
        #pragma unroll
        for (int k = 0; k < 5; ++k) {
            int i = t + k * NTHR;
            if (i < NF4) {
                int j = i / (XTLEN / 4);        // 0..7
                int c = i - j * (XTLEN / 4);    // 0..135
                int pos = c * 4;
                long gp = nbase - 16 + pos;
                const float* xr = x + (long)rel[g * JJ + j] * LL + gp;
                float v0, v1, v2, v3;
                if (gp >= 0 && gp + 3 < LL) {   // interior: one dwordx4
                    float4 v = *(const float4*)xr;
                    v0 = v.x; v1 = v.y; v2 = v.z; v3 = v.w;
                } else {                        // first/last block halo
                    v0 = (gp + 0 >= 0 && gp + 0 < LL) ? xr[0] : 0.0f;
                    v1 = (gp + 1 >= 0 && gp + 1 < LL) ? xr[1] : 0.0f;
                    v2 = (gp + 2 >= 0 && gp + 2 < LL) ? xr[2] : 0.0f;
                    v3 = (gp + 3 >= 0 && gp + 3 < LL) ? xr[3] : 0.0f;
                }
                xt[(pos + 0) * 8 + j] = f2bf(v0);
                xt[(pos + 1) * 8 + j] = f2bf(v1);
                xt[(pos + 2) * 8 + j] = f2bf(v2);
                xt[(pos + 3) * 8 + j] = f2bf(v3);
            }
        }
    }
    __syncthreads();

    const int lane = t & 63;
    const int wid  = t >> 6;      // wave 0..3, owns cols [wid*128, wid*128+128)
    const int col  = lane & 15;
    const int q    = lane >> 4;   // quad

    // P fragments (now the B operand): b[s] lane = P[g, f=col, j=0..7, w=s*4+q]
    bf16x8 b[8];
    #pragma unroll
    for (int s = 0; s < 8; ++s)
        b[s] = *(const bf16x8*)&pw[((s * 4 + q) * 16 + col) * 8];

    const int pb = wid * 128 + col + q + 1;   // lane's base xt position

    #define LDX(pos) (*(const bf16x8*)&xt[(pos) * 8])

    // Rolling window: F0 = frags(tile 2u, s=0..3)
    bf16x8 F00 = LDX(pb + 0), F01 = LDX(pb + 4), F02 = LDX(pb + 8), F03 = LDX(pb + 12);

    #pragma unroll
    for (int u = 0; u < 4; ++u) {
        const int o = pb + u * 32;
        // F1 = frags(2u, s=4..7) == frags(2u+1, s=0..3); F2 = frags(2u+1, s=4..7)
        bf16x8 F10 = LDX(o + 16), F11 = LDX(o + 20), F12 = LDX(o + 24), F13 = LDX(o + 28);
        bf16x8 F20 = LDX(o + 32), F21 = LDX(o + 36), F22 = LDX(o + 40), F23 = LDX(o + 44);

        f32x4 acc0 = {0.f, 0.f, 0.f, 0.f};
        f32x4 acc1 = {0.f, 0.f, 0.f, 0.f};
        acc0 = __builtin_amdgcn_mfma_f32_16x16x32_bf16(F00, b[0], acc0, 0, 0, 0);
        acc1 = __builtin_amdgcn_mfma_f32_16x16x32_bf16(F10, b[0], acc1, 0, 0, 0);
        acc0 = __builtin_amdgcn_mfma_f32_16x16x32_bf16(F01, b[1], acc0, 0, 0, 0);
        acc1 = __builtin_amdgcn_mfma_f32_16x16x32_bf16(F11, b[1], acc1, 0, 0, 0);
        acc0 = __builtin_amdgcn_mfma_f32_16x16x32_bf16(F02, b[2], acc0, 0, 0, 0);
        acc1 = __builtin_amdgcn_mfma_f32_16x16x32_bf16(F12, b[2], acc1, 0, 0, 0);
        acc0 = __builtin_amdgcn_mfma_f32_16x16x32_bf16(F03, b[3], acc0, 0, 0, 0);
        acc1 = __builtin_amdgcn_mfma_f32_16x16x32_bf16(F13, b[3], acc1, 0, 0, 0);
        acc0 = __builtin_amdgcn_mfma_f32_16x16x32_bf16(F10, b[4], acc0, 0, 0, 0);
        acc1 = __builtin_amdgcn_mfma_f32_16x16x32_bf16(F20, b[4], acc1, 0, 0, 0);
        acc0 = __builtin_amdgcn_mfma_f32_16x16x32_bf16(F11, b[5], acc0, 0, 0, 0);
        acc1 = __builtin_amdgcn_mfma_f32_16x16x32_bf16(F21, b[5], acc1, 0, 0, 0);
        acc0 = __builtin_amdgcn_mfma_f32_16x16x32_bf16(F12, b[6], acc0, 0, 0, 0);
        acc1 = __builtin_amdgcn_mfma_f32_16x16x32_bf16(F22, b[6], acc1, 0, 0, 0);
        acc0 = __builtin_amdgcn_mfma_f32_16x16x32_bf16(F13, b[7], acc0, 0, 0, 0);
        acc1 = __builtin_amdgcn_mfma_f32_16x16x32_bf16(F23, b[7], acc1, 0, 0, 0);

        // Swapped D layout: lane holds positions (tile*16 + q*4 .. +3) of
        // filter `col` -> one f32x4 store per tile.
        const long kc0 = nbase + (long)(wid * 128 + u * 32) + q * 4;
        const size_t ro = (size_t)(g * FGF + col) * LL;
        *(f32x4*)&out[ro + kc0]      = acc0;    // tile 2u
        *(f32x4*)&out[ro + kc0 + 16] = acc1;    // tile 2u+1

        F00 = F20; F01 = F21; F02 = F22; F03 = F23;   // roll window
    }
    #undef LDX

    // ---- merged edge fix (was a second kernel launch). Reference TRUNCATES
    // the window at the data edges (not zero-pad), so the first/last 15
    // columns computed above (from zero-padded xt) are wrong and must be
    // overwritten in exact fp32. __syncthreads() drains the main loop's
    // stores (compiler emits s_waitcnt vmcnt(0) before s_barrier), so the
    // overwrite cannot race with wave 0/3's main-loop stores.
    if (blockIdx.x == 0 || blockIdx.x == (LL / NB - 1)) {
        __syncthreads();
        const int f  = t >> 4;
        const int qq = t & 15;
        if (qq < PAD1) {
            const bool left = (blockIdx.x == 0);
            float a = 0.0f;
            for (int j = 0; j < JJ; ++j) {
                const float* pf = p + (((long)(g * FGF + f)) * JJ + j) * WW;
                const float* xj = x + (long)rel[g * JJ + j] * LL + (left ? 0 : LL - WW);
                #pragma unroll
                for (int w = 0; w < WW; ++w) {
                    // left:  y[qq]        = sum_{w <= qq+15} x[w]      * K[w]
                    // right: y[L-15+qq]   = sum_{w >= qq+1 } x[L-31+w] * K[w]
                    bool use = left ? (w <= qq + PAD1) : (w >= qq + 1);
                    if (use) a += xj[w] * pf[w];
                }
            }
            const size_t ro = (size_t)(g * FGF + f) * LL;
            out[ro + (left ? (long)qq : (long)(LL - PAD1) + qq)] = a;
        }
    }
}

extern "C" void kernel_launch(void* const* d_in, const int* in_sizes, int n_in,
                              void* d_out, int out_size, void* d_ws, size_t ws_size,
                              hipStream_t stream)
{
    const float* x   = (const float*)d_in[0];
    const float* p   = (const float*)d_in[1];
    const int*   rel = (const int*)d_in[2];
    float* out = (float*)d_out;

    dim3 grid(LL / NB, GG);
    conv_mfma<<<grid, NTHR, 0, stream>>>(x, p, rel, out);
}